// Round 1
// baseline (905.056 us; speedup 1.0000x reference)
//
#include <hip/hip_runtime.h>
#include <hip/hip_fp16.h>

#define EPS 1e-5f

constexpr int B = 4, N = 4096, C = 128, CO = 256, KNN = 16;
constexpr int M = B * N;  // 16384 points total

typedef _Float16 half8 __attribute__((ext_vector_type(8)));
typedef float f32x4 __attribute__((ext_vector_type(4)));

// ---------------------------------------------------------------------------
// Kernel 1: squared norms  sq[b,n] = sum_c x^2
// grid M/64, block 256: 4 threads per row, 32 floats each
// ---------------------------------------------------------------------------
__global__ __launch_bounds__(256) void k_sq(const float* __restrict__ x,
                                            float* __restrict__ sq) {
  int t = threadIdx.x;
  int row = blockIdx.x * 64 + (t >> 2);
  int part = t & 3;
  const float4* xr = (const float4*)(x + (size_t)row * C) + part * 8;
  float s = 0.f;
#pragma unroll
  for (int i = 0; i < 8; ++i) {
    float4 v = xr[i];
    s += v.x * v.x + v.y * v.y + v.z * v.z + v.w * v.w;
  }
  s += __shfl_xor(s, 1);
  s += __shfl_xor(s, 2);
  if (part == 0) sq[row] = s;
}

// ---------------------------------------------------------------------------
// Kernel 2: A~ = s1 * (x @ W1[0:128,:]), B~ = s1 * (x @ W1[128:256,:])
// (BN1 scale folded; bias folded later in k_mlp).
// GEMM M x 256, K=128.  grid (M/64, 256/64), block 256, 4x4 micro-tile.
// ---------------------------------------------------------------------------
__global__ __launch_bounds__(256) void k_gemm1(
    const float* __restrict__ x, const float* __restrict__ W1,
    const float* __restrict__ gamma1, const float* __restrict__ var1,
    float* __restrict__ At, float* __restrict__ Bt) {
  __shared__ float xT[64][68];  // [k][row]
  __shared__ float wS[64][68];  // [k][col]
  int t = threadIdx.x;
  int m0 = blockIdx.x * 64;
  int n0 = blockIdx.y * 64;
  float acc[4][4] = {};
  int r0 = (t & 15) * 4, c0 = (t >> 4) * 4;
  for (int k0 = 0; k0 < C; k0 += 64) {
    {
      int r = t >> 2;
      int cb = (t & 3) * 16;
      const float* src = x + (size_t)(m0 + r) * C + k0 + cb;
#pragma unroll
      for (int i = 0; i < 4; ++i) {
        float4 v = *(const float4*)(src + i * 4);
        xT[cb + i * 4 + 0][r] = v.x;
        xT[cb + i * 4 + 1][r] = v.y;
        xT[cb + i * 4 + 2][r] = v.z;
        xT[cb + i * 4 + 3][r] = v.w;
      }
      int kk = t >> 2;
      int jb = (t & 3) * 16;
      const float* wsrc = (n0 < C) ? (W1 + (size_t)(k0 + kk) * C + (n0 + jb))
                                   : (W1 + (size_t)(C + k0 + kk) * C + (n0 - C + jb));
#pragma unroll
      for (int i = 0; i < 4; ++i)
        *(float4*)&wS[kk][jb + i * 4] = *(const float4*)(wsrc + i * 4);
    }
    __syncthreads();
#pragma unroll 8
    for (int k = 0; k < 64; ++k) {
      f32x4 a = *(const f32x4*)&xT[k][r0];
      f32x4 b = *(const f32x4*)&wS[k][c0];
#pragma unroll
      for (int i = 0; i < 4; ++i)
#pragma unroll
        for (int j = 0; j < 4; ++j) acc[i][j] = fmaf(a[i], b[j], acc[i][j]);
    }
    __syncthreads();
  }
  float* dst = (n0 < C) ? At : Bt;
  int ch0 = (n0 + c0) & (C - 1);
  float s1[4];
#pragma unroll
  for (int j = 0; j < 4; ++j) s1[j] = gamma1[ch0 + j] * rsqrtf(var1[ch0 + j] + EPS);
#pragma unroll
  for (int i = 0; i < 4; ++i) {
    float4 v = make_float4(acc[i][0] * s1[0], acc[i][1] * s1[1],
                           acc[i][2] * s1[2], acc[i][3] * s1[3]);
    *(float4*)&dst[(size_t)(m0 + r0 + i) * C + ch0] = v;
  }
}

// ---------------------------------------------------------------------------
// Kernel 3: fused distance + exact top-16 (fp32, matches reference formula
// sq_n + sq_m - 2*dot for ranking).  64 query rows per block, 256 threads:
// slice = t&15 (16 interleaved m-slices, exactness preserved by union-merge),
// quad = t>>4 (4 rows each).  Per-slice top-16 in registers, butterfly
// shuffle-merge across the 16 in-wave slices at the end.
// ---------------------------------------------------------------------------
__global__ __launch_bounds__(256) void k_topk(const float* __restrict__ x,
                                              const float* __restrict__ sq,
                                              int* __restrict__ knn) {
  __shared__ float qs[64][132];  // query rows, full K
  __shared__ float xs[64][68];   // m-tile, half K
  int t = threadIdx.x;
  int b = blockIdx.x >> 6;
  int n0 = (blockIdx.x & 63) * 64;
  const float* xb = x + (size_t)b * N * C;
  const float* sqb = sq + (size_t)b * N;
  {
    int r = t >> 2;
    int cb = (t & 3) * 32;
    const float* src = xb + (size_t)(n0 + r) * C + cb;
#pragma unroll
    for (int i = 0; i < 8; ++i)
      *(float4*)&qs[r][cb + i * 4] = *(const float4*)(src + i * 4);
  }
  int slice = t & 15, quad = t >> 4;
  float sqn[4], vmax[4];
  float dl[4][16];
  int il[4][16];
#pragma unroll
  for (int i = 0; i < 4; ++i) {
    sqn[i] = sqb[n0 + quad * 4 + i];
    vmax[i] = 3e38f;
#pragma unroll
    for (int j = 0; j < 16; ++j) {
      dl[i][j] = 3e38f;
      il[i][j] = 0;
    }
  }
  __syncthreads();

  for (int m0 = 0; m0 < N; m0 += 64) {
    float smv[4];
#pragma unroll
    for (int jj = 0; jj < 4; ++jj) smv[jj] = sqb[m0 + slice + 16 * jj];
    float acc[4][4] = {};
#pragma unroll 1
    for (int half = 0; half < 2; ++half) {
      {
        int r = t >> 2;
        int cb = (t & 3) * 16;
        const float* src = xb + (size_t)(m0 + r) * C + half * 64 + cb;
#pragma unroll
        for (int i = 0; i < 4; ++i)
          *(float4*)&xs[r][cb + i * 4] = *(const float4*)(src + i * 4);
      }
      __syncthreads();
      int cbase = half * 64;
#pragma unroll
      for (int cq = 0; cq < 16; ++cq) {
        f32x4 qv[4], mv[4];
#pragma unroll
        for (int i = 0; i < 4; ++i)
          qv[i] = *(const f32x4*)&qs[quad * 4 + i][cbase + cq * 4];
#pragma unroll
        for (int jj = 0; jj < 4; ++jj)
          mv[jj] = *(const f32x4*)&xs[slice + 16 * jj][cq * 4];
#pragma unroll
        for (int i = 0; i < 4; ++i)
#pragma unroll
          for (int jj = 0; jj < 4; ++jj)
#pragma unroll
            for (int e = 0; e < 4; ++e)
              acc[i][jj] = fmaf(qv[i][e], mv[jj][e], acc[i][jj]);
      }
      __syncthreads();
    }
    // insert candidates
#pragma unroll
    for (int jj = 0; jj < 4; ++jj) {
      int mg = m0 + slice + 16 * jj;
#pragma unroll
      for (int i = 0; i < 4; ++i) {
        float key = sqn[i] + smv[jj] - 2.0f * acc[i][jj];
        if (key < vmax[i]) {
          bool done = false;
#pragma unroll
          for (int j = 0; j < 16; ++j) {
            bool take = (!done) && (dl[i][j] == vmax[i]);
            if (take) {
              dl[i][j] = key;
              il[i][j] = mg;
            }
            done |= take;
          }
          float nv = dl[i][0];
#pragma unroll
          for (int j = 1; j < 16; ++j) nv = fmaxf(nv, dl[i][j]);
          vmax[i] = nv;
        }
      }
    }
  }

  // butterfly merge across 16 slices (lanes differing in low 4 bits)
#pragma unroll
  for (int step = 1; step <= 8; step <<= 1) {
#pragma unroll
    for (int i = 0; i < 4; ++i) {
      float pd[16];
      int pi[16];
#pragma unroll
      for (int j = 0; j < 16; ++j) {
        pd[j] = __shfl_xor(dl[i][j], step);
        pi[j] = __shfl_xor(il[i][j], step);
      }
#pragma unroll
      for (int j = 0; j < 16; ++j) {
        if (pd[j] < vmax[i]) {
          bool done = false;
#pragma unroll
          for (int jj = 0; jj < 16; ++jj) {
            bool take = (!done) && (dl[i][jj] == vmax[i]);
            if (take) {
              dl[i][jj] = pd[j];
              il[i][jj] = pi[j];
            }
            done |= take;
          }
          float nv = dl[i][0];
#pragma unroll
          for (int jj = 1; jj < 16; ++jj) nv = fmaxf(nv, dl[i][jj]);
          vmax[i] = nv;
        }
      }
    }
  }

  if (slice == 0) {
    int base = (b * N + n0 + quad * 4) * KNN;
#pragma unroll
    for (int i = 0; i < 4; ++i)
#pragma unroll
      for (int j = 0; j < 16; ++j) knn[base + i * KNN + j] = il[i][j];
  }
}

// ---------------------------------------------------------------------------
// Kernel 4: per point: h[k][c] = relu(A~ + B~[idx_k] + beta_f) (f16 to LDS),
// then y[16,256] = h @ W2 via mfma_f32_16x16x32_f16 (M=16 rows = k-slots),
// BN2 affine, max over rows -> out[256].  16 points per block, 4 waves,
// each wave owns 64 output channels with W2 fragments resident in VGPRs.
// ---------------------------------------------------------------------------
__global__ __launch_bounds__(256) void k_mlp(
    const float* __restrict__ At, const float* __restrict__ Bt,
    const int* __restrict__ knn, const float* __restrict__ W2,
    const float* __restrict__ b1, const float* __restrict__ mean1,
    const float* __restrict__ beta1, const float* __restrict__ gamma1,
    const float* __restrict__ var1, const float* __restrict__ b2,
    const float* __restrict__ mean2, const float* __restrict__ beta2,
    const float* __restrict__ gamma2, const float* __restrict__ var2,
    float* __restrict__ out) {
  __shared__ _Float16 hl[16][136];  // +8 halfs pad: 2-way-max banks on frag reads
  int t = threadIdx.x;
  int lane = t & 63;
  int wave = t >> 6;
  int hk = t >> 4;         // k-slot this thread fills
  int hc = (t & 15) * 8;   // c-chunk this thread fills

  float beta_f[8];
#pragma unroll
  for (int e = 0; e < 8; ++e) {
    int c = hc + e;
    float s1 = gamma1[c] * rsqrtf(var1[c] + EPS);
    beta_f[e] = s1 * (b1[c] - mean1[c]) + beta1[c];
  }
  float s2r[4], t2r[4];
#pragma unroll
  for (int nt = 0; nt < 4; ++nt) {
    int ch = wave * 64 + nt * 16 + (lane & 15);
    float s2 = gamma2[ch] * rsqrtf(var2[ch] + EPS);
    s2r[nt] = s2;
    t2r[nt] = s2 * (b2[ch] - mean2[ch]) + beta2[ch];
  }
  // W2 fragments: B[k][n], k = ks*32 + (lane>>4)*8 + i, n = lane&15 (per ntile)
  half8 bf[4][4];
#pragma unroll
  for (int nt = 0; nt < 4; ++nt)
#pragma unroll
    for (int ks = 0; ks < 4; ++ks) {
      int col = wave * 64 + nt * 16 + (lane & 15);
      int kb = ks * 32 + (lane >> 4) * 8;
      half8 hv;
#pragma unroll
      for (int i = 0; i < 8; ++i) hv[i] = (_Float16)W2[(size_t)(kb + i) * CO + col];
      bf[nt][ks] = hv;
    }

  int p0 = blockIdx.x * 16;
  for (int p = 0; p < 16; ++p) {
    int pt = p0 + p;
    int m = knn[(size_t)pt * KNN + hk];
    int bb = pt >> 12;
    const float* arow = At + (size_t)pt * C + hc;
    const float* brow = Bt + ((size_t)(bb << 12) + m) * C + hc;
    float4 a0 = *(const float4*)(arow);
    float4 a1 = *(const float4*)(arow + 4);
    float4 g0 = *(const float4*)(brow);
    float4 g1 = *(const float4*)(brow + 4);
    float vv[8] = {a0.x + g0.x, a0.y + g0.y, a0.z + g0.z, a0.w + g0.w,
                   a1.x + g1.x, a1.y + g1.y, a1.z + g1.z, a1.w + g1.w};
    half8 hh;
#pragma unroll
    for (int e = 0; e < 8; ++e) hh[e] = (_Float16)fmaxf(vv[e] + beta_f[e], 0.f);
    *(half8*)&hl[hk][hc] = hh;
    __syncthreads();

    f32x4 acc[4] = {};
    half8 af[4];
#pragma unroll
    for (int ks = 0; ks < 4; ++ks)
      af[ks] = *(const half8*)&hl[lane & 15][ks * 32 + (lane >> 4) * 8];
#pragma unroll
    for (int nt = 0; nt < 4; ++nt)
#pragma unroll
      for (int ks = 0; ks < 4; ++ks)
        acc[nt] = __builtin_amdgcn_mfma_f32_16x16x32_f16(af[ks], bf[nt][ks],
                                                         acc[nt], 0, 0, 0);
    // max over the 16 D-rows (= k slots): rows (lane>>4)*4 + reg
#pragma unroll
    for (int nt = 0; nt < 4; ++nt) {
      float v = fmaxf(fmaxf(acc[nt][0], acc[nt][1]), fmaxf(acc[nt][2], acc[nt][3]));
      v = fmaxf(v, __shfl_xor(v, 16));
      v = fmaxf(v, __shfl_xor(v, 32));
      float o = fmaf(v, s2r[nt], t2r[nt]);
      if (lane < 16) out[(size_t)pt * CO + wave * 64 + nt * 16 + lane] = o;
    }
    __syncthreads();
  }
}

// ---------------------------------------------------------------------------
extern "C" void kernel_launch(void* const* d_in, const int* in_sizes, int n_in,
                              void* d_out, int out_size, void* d_ws, size_t ws_size,
                              hipStream_t stream) {
  const float* x = (const float*)d_in[0];
  const float* W1 = (const float*)d_in[1];
  const float* b1 = (const float*)d_in[2];
  const float* gamma1 = (const float*)d_in[3];
  const float* beta1 = (const float*)d_in[4];
  const float* mean1 = (const float*)d_in[5];
  const float* var1 = (const float*)d_in[6];
  const float* W2 = (const float*)d_in[7];
  const float* b2 = (const float*)d_in[8];
  const float* gamma2 = (const float*)d_in[9];
  const float* beta2 = (const float*)d_in[10];
  const float* mean2 = (const float*)d_in[11];
  const float* var2 = (const float*)d_in[12];
  float* out = (float*)d_out;

  float* At = (float*)d_ws;                 // [M][128]
  float* Bt = At + (size_t)M * C;           // [M][128]
  float* sq = Bt + (size_t)M * C;           // [M]
  int* knn = (int*)(sq + M);                // [M][16]

  k_sq<<<dim3(M / 64), dim3(256), 0, stream>>>(x, sq);
  k_gemm1<<<dim3(M / 64, CO / 64), dim3(256), 0, stream>>>(x, W1, gamma1, var1, At, Bt);
  k_topk<<<dim3(B * (N / 64)), dim3(256), 0, stream>>>(x, sq, knn);
  k_mlp<<<dim3(M / 16), dim3(256), 0, stream>>>(At, Bt, knn, W2, b1, mean1, beta1,
                                                gamma1, var1, b2, mean2, beta2,
                                                gamma2, var2, out);
}

// Round 5
// 446.518 us; speedup vs baseline: 2.0269x; 2.0269x over previous
//
#include <hip/hip_runtime.h>
#include <hip/hip_fp16.h>

#define EPS 1e-5f

constexpr int B = 4, N = 4096, C = 128, CO = 256, KNN = 16;
constexpr int M = B * N;  // 16384 points total
constexpr int CHUNK = 1024, NCHUNK = 4;

typedef _Float16 half8 __attribute__((ext_vector_type(8)));
typedef float f32x4 __attribute__((ext_vector_type(4)));

// top-16 insertion: list kept as "16 best so far", vmax = current worst.
__device__ __forceinline__ void ins16(float key, int idx, float (&dl)[16],
                                      int (&il)[16], float& vmax) {
  if (key < vmax) {
    bool done = false;
#pragma unroll
    for (int j = 0; j < 16; ++j) {
      bool take = (!done) && (dl[j] == vmax);
      if (take) {
        dl[j] = key;
        il[j] = idx;
      }
      done |= take;
    }
    float nv = dl[0];
#pragma unroll
    for (int j = 1; j < 16; ++j) nv = fmaxf(nv, dl[j]);
    vmax = nv;
  }
}

// ---------------------------------------------------------------------------
// Kernel 1: split x into f16 hi/lo (x = h + m exactly to ~2^-22) + sq norms.
// ---------------------------------------------------------------------------
__global__ __launch_bounds__(256) void k_cvt(const float* __restrict__ x,
                                             _Float16* __restrict__ xh,
                                             _Float16* __restrict__ xm,
                                             float* __restrict__ sq) {
  int t = threadIdx.x;
  int row = blockIdx.x * 64 + (t >> 2);
  int part = t & 3;
  const float* src = x + (size_t)row * C + part * 32;
  _Float16* dh = xh + (size_t)row * C + part * 32;
  _Float16* dm = xm + (size_t)row * C + part * 32;
  float s = 0.f;
#pragma unroll
  for (int i = 0; i < 4; ++i) {
    float4 v0 = *(const float4*)(src + i * 8);
    float4 v1 = *(const float4*)(src + i * 8 + 4);
    float vv[8] = {v0.x, v0.y, v0.z, v0.w, v1.x, v1.y, v1.z, v1.w};
    half8 h, m;
#pragma unroll
    for (int e = 0; e < 8; ++e) {
      s += vv[e] * vv[e];
      _Float16 hh = (_Float16)vv[e];
      h[e] = hh;
      m[e] = (_Float16)(vv[e] - (float)hh);
    }
    *(half8*)(dh + i * 8) = h;
    *(half8*)(dm + i * 8) = m;
  }
  s += __shfl_xor(s, 1);
  s += __shfl_xor(s, 2);
  if (part == 0) sq[row] = s;
}

// ---------------------------------------------------------------------------
// Kernel 2: MFMA distance + per-chunk exact top-16.
// Gram via 3-pass f16-split mfma_f32_16x16x32_f16 (A=candidates, B=queries;
// layouts identical to the validated k_mlp usage).  Block: 4 waves x 32
// queries (2 tiles of 16), all waves scan the block's 1024-candidate chunk
// staged tile-by-tile (16 cands) in double-buffered LDS.  Per-lane top-16
// list for query col=lane&15 over its row-quarter; quad-merge via shfl at
// end; partial lists to pd/pi.
// ---------------------------------------------------------------------------
__global__ __launch_bounds__(256) void k_topk(
    const _Float16* __restrict__ xh, const _Float16* __restrict__ xm,
    const float* __restrict__ sq, float* __restrict__ pd, int* __restrict__ pi) {
  __shared__ _Float16 hs[2][16][136];  // pad 8 halfs: uniform bank spread
  __shared__ _Float16 ms[2][16][136];
  int t = threadIdx.x;
  int lane = t & 63, w = t >> 6;
  int bi = blockIdx.x;
  int chunk = bi & 3;
  int qg = (bi >> 2) & 31;
  int b = bi >> 7;
  int col = lane & 15, quad = lane >> 4;
  int qbase = qg * 128 + w * 32;
  const _Float16* xhb = xh + (size_t)b * N * C;
  const _Float16* xmb = xm + (size_t)b * N * C;
  const float* sqb = sq + (size_t)b * N;

  // resident query fragments (B operand): col=lane&15, k=(lane>>4)*8+i
  half8 bh[2][4], bm[2][4];
  float sqn[2];
#pragma unroll
  for (int qt = 0; qt < 2; ++qt) {
    int qr = qbase + qt * 16 + col;
    sqn[qt] = sqb[qr];
#pragma unroll
    for (int kst = 0; kst < 4; ++kst) {
      bh[qt][kst] = *(const half8*)(xhb + (size_t)qr * C + kst * 32 + quad * 8);
      bm[qt][kst] = *(const half8*)(xmb + (size_t)qr * C + kst * 32 + quad * 8);
    }
  }
  float dl[2][16];
  int il[2][16];
  float vmax[2];
#pragma unroll
  for (int qt = 0; qt < 2; ++qt) {
    vmax[qt] = 3e38f;
#pragma unroll
    for (int j = 0; j < 16; ++j) {
      dl[qt][j] = 3e38f;
      il[qt][j] = 0;
    }
  }
  int mbase = chunk * CHUNK;
  int sr = t & 15, sko = (t >> 4) * 8;  // staging assignment

  *(half8*)&hs[0][sr][sko] = *(const half8*)(xhb + (size_t)(mbase + sr) * C + sko);
  *(half8*)&ms[0][sr][sko] = *(const half8*)(xmb + (size_t)(mbase + sr) * C + sko);
  __syncthreads();

  for (int tile = 0; tile < CHUNK / 16; ++tile) {
    int buf = tile & 1;
    if (tile + 1 < CHUNK / 16) {  // prefetch next tile into other buffer
      int m1 = mbase + (tile + 1) * 16;
      *(half8*)&hs[buf ^ 1][sr][sko] = *(const half8*)(xhb + (size_t)(m1 + sr) * C + sko);
      *(half8*)&ms[buf ^ 1][sr][sko] = *(const half8*)(xmb + (size_t)(m1 + sr) * C + sko);
    }
    int m0 = mbase + tile * 16;
    f32x4 a0[2] = {};  // hh accumulation
    f32x4 a1[2] = {};  // mh + hm accumulation
#pragma unroll
    for (int kst = 0; kst < 4; ++kst) {
      half8 ah = *(const half8*)&hs[buf][col][kst * 32 + quad * 8];
      half8 am = *(const half8*)&ms[buf][col][kst * 32 + quad * 8];
#pragma unroll
      for (int qt = 0; qt < 2; ++qt) {
        a0[qt] = __builtin_amdgcn_mfma_f32_16x16x32_f16(ah, bh[qt][kst], a0[qt], 0, 0, 0);
        a1[qt] = __builtin_amdgcn_mfma_f32_16x16x32_f16(am, bh[qt][kst], a1[qt], 0, 0, 0);
        a1[qt] = __builtin_amdgcn_mfma_f32_16x16x32_f16(ah, bm[qt][kst], a1[qt], 0, 0, 0);
      }
    }
    float4 sqm = *(const float4*)(sqb + m0 + quad * 4);
    float sqmv[4] = {sqm.x, sqm.y, sqm.z, sqm.w};
#pragma unroll
    for (int qt = 0; qt < 2; ++qt)
#pragma unroll
      for (int j = 0; j < 4; ++j) {
        float key = sqn[qt] + sqmv[j] - 2.0f * (a0[qt][j] + a1[qt][j]);
        ins16(key, m0 + quad * 4 + j, dl[qt], il[qt], vmax[qt]);
      }
    __syncthreads();
  }

  // merge the 4 row-quarters (lanes col, col+16, col+32, col+48)
#pragma unroll
  for (int step = 16; step <= 32; step <<= 1) {
#pragma unroll
    for (int qt = 0; qt < 2; ++qt) {
      float pdx[16];
      int pix[16];
#pragma unroll
      for (int j = 0; j < 16; ++j) {
        pdx[j] = __shfl_xor(dl[qt][j], step);
        pix[j] = __shfl_xor(il[qt][j], step);
      }
#pragma unroll
      for (int j = 0; j < 16; ++j) ins16(pdx[j], pix[j], dl[qt], il[qt], vmax[qt]);
    }
  }

  if (quad == 0) {
#pragma unroll
    for (int qt = 0; qt < 2; ++qt) {
      size_t q = (size_t)b * N + qbase + qt * 16 + col;
#pragma unroll
      for (int j = 0; j < 16; ++j) {
        pd[(q * NCHUNK + chunk) * 16 + j] = dl[qt][j];
        pi[(q * NCHUNK + chunk) * 16 + j] = il[qt][j];
      }
    }
  }
}

// ---------------------------------------------------------------------------
// Kernel 3: merge 4 partial lists (64 candidates) -> final top-16 per query.
// ---------------------------------------------------------------------------
__global__ __launch_bounds__(256) void k_merge(const float* __restrict__ pd,
                                               const int* __restrict__ pi,
                                               int* __restrict__ knn) {
  int q = blockIdx.x * 256 + threadIdx.x;
  float dl[16];
  int il[16];
  float vmax = 3e38f;
#pragma unroll
  for (int j = 0; j < 16; ++j) {
    dl[j] = 3e38f;
    il[j] = 0;
  }
  const float* pdq = pd + (size_t)q * (NCHUNK * 16);
  const int* piq = pi + (size_t)q * (NCHUNK * 16);
#pragma unroll 4
  for (int c = 0; c < NCHUNK * 16; ++c) ins16(pdq[c], piq[c], dl, il, vmax);
#pragma unroll
  for (int j = 0; j < 16; ++j) knn[(size_t)q * KNN + j] = il[j];
}

// ---------------------------------------------------------------------------
// Kernel 4: A~ = s1 * (x @ W1[0:128,:]), B~ = s1 * (x @ W1[128:256,:])
// ---------------------------------------------------------------------------
__global__ __launch_bounds__(256) void k_gemm1(
    const float* __restrict__ x, const float* __restrict__ W1,
    const float* __restrict__ gamma1, const float* __restrict__ var1,
    float* __restrict__ At, float* __restrict__ Bt) {
  __shared__ float xT[64][68];  // [k][row]
  __shared__ float wS[64][68];  // [k][col]
  int t = threadIdx.x;
  int m0 = blockIdx.x * 64;
  int n0 = blockIdx.y * 64;
  float acc[4][4] = {};
  int r0 = (t & 15) * 4, c0 = (t >> 4) * 4;
  for (int k0 = 0; k0 < C; k0 += 64) {
    {
      int r = t >> 2;
      int cb = (t & 3) * 16;
      const float* src = x + (size_t)(m0 + r) * C + k0 + cb;
#pragma unroll
      for (int i = 0; i < 4; ++i) {
        float4 v = *(const float4*)(src + i * 4);
        xT[cb + i * 4 + 0][r] = v.x;
        xT[cb + i * 4 + 1][r] = v.y;
        xT[cb + i * 4 + 2][r] = v.z;
        xT[cb + i * 4 + 3][r] = v.w;
      }
      int kk = t >> 2;
      int jb = (t & 3) * 16;
      const float* wsrc = (n0 < C) ? (W1 + (size_t)(k0 + kk) * C + (n0 + jb))
                                   : (W1 + (size_t)(C + k0 + kk) * C + (n0 - C + jb));
#pragma unroll
      for (int i = 0; i < 4; ++i)
        *(float4*)&wS[kk][jb + i * 4] = *(const float4*)(wsrc + i * 4);
    }
    __syncthreads();
#pragma unroll 8
    for (int k = 0; k < 64; ++k) {
      f32x4 a = *(const f32x4*)&xT[k][r0];
      f32x4 b = *(const f32x4*)&wS[k][c0];
#pragma unroll
      for (int i = 0; i < 4; ++i)
#pragma unroll
        for (int j = 0; j < 4; ++j) acc[i][j] = fmaf(a[i], b[j], acc[i][j]);
    }
    __syncthreads();
  }
  float* dst = (n0 < C) ? At : Bt;
  int ch0 = (n0 + c0) & (C - 1);
  float s1[4];
#pragma unroll
  for (int j = 0; j < 4; ++j) s1[j] = gamma1[ch0 + j] * rsqrtf(var1[ch0 + j] + EPS);
#pragma unroll
  for (int i = 0; i < 4; ++i) {
    float4 v = make_float4(acc[i][0] * s1[0], acc[i][1] * s1[1],
                           acc[i][2] * s1[2], acc[i][3] * s1[3]);
    *(float4*)&dst[(size_t)(m0 + r0 + i) * C + ch0] = v;
  }
}

// ---------------------------------------------------------------------------
// Kernel 5: per point h = relu(A~ + B~[idx] + beta_f) -> f16, y = h @ W2
// via mfma 16x16x32, BN2 affine, max over k -> out.
// ---------------------------------------------------------------------------
__global__ __launch_bounds__(256) void k_mlp(
    const float* __restrict__ At, const float* __restrict__ Bt,
    const int* __restrict__ knn, const float* __restrict__ W2,
    const float* __restrict__ b1, const float* __restrict__ mean1,
    const float* __restrict__ beta1, const float* __restrict__ gamma1,
    const float* __restrict__ var1, const float* __restrict__ b2,
    const float* __restrict__ mean2, const float* __restrict__ beta2,
    const float* __restrict__ gamma2, const float* __restrict__ var2,
    float* __restrict__ out) {
  __shared__ _Float16 hl[16][136];
  int t = threadIdx.x;
  int lane = t & 63;
  int wave = t >> 6;
  int hk = t >> 4;
  int hc = (t & 15) * 8;

  float beta_f[8];
#pragma unroll
  for (int e = 0; e < 8; ++e) {
    int c = hc + e;
    float s1 = gamma1[c] * rsqrtf(var1[c] + EPS);
    beta_f[e] = s1 * (b1[c] - mean1[c]) + beta1[c];
  }
  float s2r[4], t2r[4];
#pragma unroll
  for (int nt = 0; nt < 4; ++nt) {
    int ch = wave * 64 + nt * 16 + (lane & 15);
    float s2 = gamma2[ch] * rsqrtf(var2[ch] + EPS);
    s2r[nt] = s2;
    t2r[nt] = s2 * (b2[ch] - mean2[ch]) + beta2[ch];
  }
  half8 bf[4][4];
#pragma unroll
  for (int nt = 0; nt < 4; ++nt)
#pragma unroll
    for (int ks = 0; ks < 4; ++ks) {
      int colc = wave * 64 + nt * 16 + (lane & 15);
      int kb = ks * 32 + (lane >> 4) * 8;
      half8 hv;
#pragma unroll
      for (int i = 0; i < 8; ++i) hv[i] = (_Float16)W2[(size_t)(kb + i) * CO + colc];
      bf[nt][ks] = hv;
    }

  int p0 = blockIdx.x * 16;
  for (int p = 0; p < 16; ++p) {
    int pt = p0 + p;
    int m = knn[(size_t)pt * KNN + hk];
    int bb = pt >> 12;
    const float* arow = At + (size_t)pt * C + hc;
    const float* brow = Bt + ((size_t)(bb << 12) + m) * C + hc;
    float4 a0 = *(const float4*)(arow);
    float4 a1 = *(const float4*)(arow + 4);
    float4 g0 = *(const float4*)(brow);
    float4 g1 = *(const float4*)(brow + 4);
    float vv[8] = {a0.x + g0.x, a0.y + g0.y, a0.z + g0.z, a0.w + g0.w,
                   a1.x + g1.x, a1.y + g1.y, a1.z + g1.z, a1.w + g1.w};
    half8 hh;
#pragma unroll
    for (int e = 0; e < 8; ++e) hh[e] = (_Float16)fmaxf(vv[e] + beta_f[e], 0.f);
    *(half8*)&hl[hk][hc] = hh;
    __syncthreads();

    f32x4 acc[4] = {};
    half8 af[4];
#pragma unroll
    for (int ks = 0; ks < 4; ++ks)
      af[ks] = *(const half8*)&hl[lane & 15][ks * 32 + (lane >> 4) * 8];
#pragma unroll
    for (int nt = 0; nt < 4; ++nt)
#pragma unroll
      for (int ks = 0; ks < 4; ++ks)
        acc[nt] = __builtin_amdgcn_mfma_f32_16x16x32_f16(af[ks], bf[nt][ks],
                                                         acc[nt], 0, 0, 0);
#pragma unroll
    for (int nt = 0; nt < 4; ++nt) {
      float v = fmaxf(fmaxf(acc[nt][0], acc[nt][1]), fmaxf(acc[nt][2], acc[nt][3]));
      v = fmaxf(v, __shfl_xor(v, 16));
      v = fmaxf(v, __shfl_xor(v, 32));
      float o = fmaf(v, s2r[nt], t2r[nt]);
      if (lane < 16) out[(size_t)pt * CO + wave * 64 + nt * 16 + lane] = o;
    }
    __syncthreads();
  }
}

// ---------------------------------------------------------------------------
extern "C" void kernel_launch(void* const* d_in, const int* in_sizes, int n_in,
                              void* d_out, int out_size, void* d_ws, size_t ws_size,
                              hipStream_t stream) {
  const float* x = (const float*)d_in[0];
  const float* W1 = (const float*)d_in[1];
  const float* b1 = (const float*)d_in[2];
  const float* gamma1 = (const float*)d_in[3];
  const float* beta1 = (const float*)d_in[4];
  const float* mean1 = (const float*)d_in[5];
  const float* var1 = (const float*)d_in[6];
  const float* W2 = (const float*)d_in[7];
  const float* b2 = (const float*)d_in[8];
  const float* gamma2 = (const float*)d_in[9];
  const float* beta2 = (const float*)d_in[10];
  const float* mean2 = (const float*)d_in[11];
  const float* var2 = (const float*)d_in[12];
  float* out = (float*)d_out;

  char* base = (char*)d_ws;
  // region A (8 MB): pd+pi during topk, then At for the MLP
  float* At = (float*)base;                       // [M][128]
  float* pd = (float*)base;                       // [M][64]
  int* pi = (int*)(base + (size_t)M * 64 * 4);    // [M][64]
  // region B (8 MB): xh+xm during topk, then Bt
  float* Bt = (float*)(base + (size_t)M * C * 4);             // [M][128]
  _Float16* xh = (_Float16*)(base + (size_t)M * C * 4);       // [M][128] f16
  _Float16* xm = xh + (size_t)M * C;                          // [M][128] f16
  // tail
  float* sq = (float*)(base + (size_t)2 * M * C * 4);         // [M]
  int* knn = (int*)(sq + M);                                  // [M][16]

  k_cvt<<<dim3(M / 64), dim3(256), 0, stream>>>(x, xh, xm, sq);
  k_topk<<<dim3(B * 32 * NCHUNK), dim3(256), 0, stream>>>(xh, xm, sq, pd, pi);
  k_merge<<<dim3(M / 256), dim3(256), 0, stream>>>(pd, pi, knn);
  k_gemm1<<<dim3(M / 64, CO / 64), dim3(256), 0, stream>>>(x, W1, gamma1, var1, At, Bt);
  k_mlp<<<dim3(M / 16), dim3(256), 0, stream>>>(At, Bt, knn, W2, b1, mean1, beta1,
                                                gamma1, var1, b2, mean2, beta2,
                                                gamma2, var2, out);
}

// Round 8
// 421.957 us; speedup vs baseline: 2.1449x; 1.0582x over previous
//
#include <hip/hip_runtime.h>
#include <hip/hip_fp16.h>

#define EPS 1e-5f

constexpr int B = 4, N = 4096, C = 128, CO = 256, KNN = 16;
constexpr int M = B * N;  // 16384 points total
constexpr int CHUNK = 1024, NCHUNK = 4;

typedef _Float16 half8 __attribute__((ext_vector_type(8)));
typedef float f32x4 __attribute__((ext_vector_type(4)));

// top-16 insertion: list kept as "16 best so far", vmax = current worst.
__device__ __forceinline__ void ins16(float key, int idx, float (&dl)[16],
                                      int (&il)[16], float& vmax) {
  if (key < vmax) {
    bool done = false;
#pragma unroll
    for (int j = 0; j < 16; ++j) {
      bool take = (!done) && (dl[j] == vmax);
      if (take) {
        dl[j] = key;
        il[j] = idx;
      }
      done |= take;
    }
    float nv = dl[0];
#pragma unroll
    for (int j = 1; j < 16; ++j) nv = fmaxf(nv, dl[j]);
    vmax = nv;
  }
}

// ---------------------------------------------------------------------------
// Kernel 1: split x into f16 hi/lo (x = h + m exactly to ~2^-22) + sq norms.
// ---------------------------------------------------------------------------
__global__ __launch_bounds__(256) void k_cvt(const float* __restrict__ x,
                                             _Float16* __restrict__ xh,
                                             _Float16* __restrict__ xm,
                                             float* __restrict__ sq) {
  int t = threadIdx.x;
  int row = blockIdx.x * 64 + (t >> 2);
  int part = t & 3;
  const float* src = x + (size_t)row * C + part * 32;
  _Float16* dh = xh + (size_t)row * C + part * 32;
  _Float16* dm = xm + (size_t)row * C + part * 32;
  float s = 0.f;
#pragma unroll
  for (int i = 0; i < 4; ++i) {
    float4 v0 = *(const float4*)(src + i * 8);
    float4 v1 = *(const float4*)(src + i * 8 + 4);
    float vv[8] = {v0.x, v0.y, v0.z, v0.w, v1.x, v1.y, v1.z, v1.w};
    half8 h, m;
#pragma unroll
    for (int e = 0; e < 8; ++e) {
      s += vv[e] * vv[e];
      _Float16 hh = (_Float16)vv[e];
      h[e] = hh;
      m[e] = (_Float16)(vv[e] - (float)hh);
    }
    *(half8*)(dh + i * 8) = h;
    *(half8*)(dm + i * 8) = m;
  }
  s += __shfl_xor(s, 1);
  s += __shfl_xor(s, 2);
  if (part == 0) sq[row] = s;
}

// ---------------------------------------------------------------------------
// Kernel 2: MFMA distance + per-chunk exact top-16.
// 16 queries per wave (1 MFMA query-tile), 4 waves/block = 64 queries/block,
// 4 candidate chunks -> grid 1024 (4 blocks/CU, was the 2/CU occupancy limit).
// Per-lane top-16 list for query col=lane&15 over its row-quarter; quad-merge
// via shfl at end; partial lists to pd/pi in transposed [c][q] layout so
// k_merge reads coalesce.
// ---------------------------------------------------------------------------
__global__ __launch_bounds__(256) void k_topk(
    const _Float16* __restrict__ xh, const _Float16* __restrict__ xm,
    const float* __restrict__ sq, float* __restrict__ pd, int* __restrict__ pi) {
  __shared__ _Float16 hs[2][16][136];  // pad 8 halfs: uniform bank spread
  __shared__ _Float16 ms[2][16][136];
  int t = threadIdx.x;
  int lane = t & 63, w = t >> 6;
  int bi = blockIdx.x;
  int chunk = bi & 3;
  int qg = (bi >> 2) & 63;
  int b = bi >> 8;
  int col = lane & 15, quad = lane >> 4;
  int qbase = qg * 64 + w * 16;
  const _Float16* xhb = xh + (size_t)b * N * C;
  const _Float16* xmb = xm + (size_t)b * N * C;
  const float* sqb = sq + (size_t)b * N;

  // resident query fragments (B operand): col=lane&15, k=(lane>>4)*8+i
  half8 bh[4], bm[4];
  int qr = qbase + col;
  float sqn = sqb[qr];
#pragma unroll
  for (int kst = 0; kst < 4; ++kst) {
    bh[kst] = *(const half8*)(xhb + (size_t)qr * C + kst * 32 + quad * 8);
    bm[kst] = *(const half8*)(xmb + (size_t)qr * C + kst * 32 + quad * 8);
  }
  float dl[16];
  int il[16];
  float vmax = 3e38f;
#pragma unroll
  for (int j = 0; j < 16; ++j) {
    dl[j] = 3e38f;
    il[j] = 0;
  }
  int mbase = chunk * CHUNK;
  int sr = t & 15, sko = (t >> 4) * 8;  // staging assignment

  *(half8*)&hs[0][sr][sko] = *(const half8*)(xhb + (size_t)(mbase + sr) * C + sko);
  *(half8*)&ms[0][sr][sko] = *(const half8*)(xmb + (size_t)(mbase + sr) * C + sko);
  __syncthreads();

  for (int tile = 0; tile < CHUNK / 16; ++tile) {
    int buf = tile & 1;
    if (tile + 1 < CHUNK / 16) {  // prefetch next tile into other buffer
      int m1 = mbase + (tile + 1) * 16;
      *(half8*)&hs[buf ^ 1][sr][sko] = *(const half8*)(xhb + (size_t)(m1 + sr) * C + sko);
      *(half8*)&ms[buf ^ 1][sr][sko] = *(const half8*)(xmb + (size_t)(m1 + sr) * C + sko);
    }
    int m0 = mbase + tile * 16;
    f32x4 a0 = {};  // hh accumulation
    f32x4 a1 = {};  // mh + hm accumulation
#pragma unroll
    for (int kst = 0; kst < 4; ++kst) {
      half8 ah = *(const half8*)&hs[buf][col][kst * 32 + quad * 8];
      half8 am = *(const half8*)&ms[buf][col][kst * 32 + quad * 8];
      a0 = __builtin_amdgcn_mfma_f32_16x16x32_f16(ah, bh[kst], a0, 0, 0, 0);
      a1 = __builtin_amdgcn_mfma_f32_16x16x32_f16(am, bh[kst], a1, 0, 0, 0);
      a1 = __builtin_amdgcn_mfma_f32_16x16x32_f16(ah, bm[kst], a1, 0, 0, 0);
    }
    float4 sqm = *(const float4*)(sqb + m0 + quad * 4);
    float sqmv[4] = {sqm.x, sqm.y, sqm.z, sqm.w};
#pragma unroll
    for (int j = 0; j < 4; ++j) {
      float key = sqn + sqmv[j] - 2.0f * (a0[j] + a1[j]);
      ins16(key, m0 + quad * 4 + j, dl, il, vmax);
    }
    __syncthreads();
  }

  // merge the 4 row-quarters (lanes col, col+16, col+32, col+48)
#pragma unroll
  for (int step = 16; step <= 32; step <<= 1) {
    float pdx[16];
    int pix[16];
#pragma unroll
    for (int j = 0; j < 16; ++j) {
      pdx[j] = __shfl_xor(dl[j], step);
      pix[j] = __shfl_xor(il[j], step);
    }
#pragma unroll
    for (int j = 0; j < 16; ++j) ins16(pdx[j], pix[j], dl, il, vmax);
  }

  if (quad == 0) {
    int q = b * N + qbase + col;  // global query id in [0, M)
#pragma unroll
    for (int j = 0; j < 16; ++j) {
      pd[(size_t)(chunk * 16 + j) * M + q] = dl[j];
      pi[(size_t)(chunk * 16 + j) * M + q] = il[j];
    }
  }
}

// ---------------------------------------------------------------------------
// Kernel 3: merge 4 partial lists (64 candidates) -> final top-16 per query.
// pd/pi are [c][q] so consecutive threads read consecutive addresses.
// ---------------------------------------------------------------------------
__global__ __launch_bounds__(256) void k_merge(const float* __restrict__ pd,
                                               const int* __restrict__ pi,
                                               int* __restrict__ knn) {
  int q = blockIdx.x * 256 + threadIdx.x;
  float dl[16];
  int il[16];
  float vmax = 3e38f;
#pragma unroll
  for (int j = 0; j < 16; ++j) {
    dl[j] = 3e38f;
    il[j] = 0;
  }
#pragma unroll 4
  for (int c = 0; c < NCHUNK * 16; ++c)
    ins16(pd[(size_t)c * M + q], pi[(size_t)c * M + q], dl, il, vmax);
#pragma unroll
  for (int j = 0; j < 16; ++j) knn[(size_t)q * KNN + j] = il[j];
}

// ---------------------------------------------------------------------------
// Kernel 4: A~ = s1 * (x @ W1[0:128,:]), B~ = s1 * (x @ W1[128:256,:])
// ---------------------------------------------------------------------------
__global__ __launch_bounds__(256) void k_gemm1(
    const float* __restrict__ x, const float* __restrict__ W1,
    const float* __restrict__ gamma1, const float* __restrict__ var1,
    float* __restrict__ At, float* __restrict__ Bt) {
  __shared__ float xT[64][68];  // [k][row]
  __shared__ float wS[64][68];  // [k][col]
  int t = threadIdx.x;
  int m0 = blockIdx.x * 64;
  int n0 = blockIdx.y * 64;
  float acc[4][4] = {};
  int r0 = (t & 15) * 4, c0 = (t >> 4) * 4;
  for (int k0 = 0; k0 < C; k0 += 64) {
    {
      int r = t >> 2;
      int cb = (t & 3) * 16;
      const float* src = x + (size_t)(m0 + r) * C + k0 + cb;
#pragma unroll
      for (int i = 0; i < 4; ++i) {
        float4 v = *(const float4*)(src + i * 4);
        xT[cb + i * 4 + 0][r] = v.x;
        xT[cb + i * 4 + 1][r] = v.y;
        xT[cb + i * 4 + 2][r] = v.z;
        xT[cb + i * 4 + 3][r] = v.w;
      }
      int kk = t >> 2;
      int jb = (t & 3) * 16;
      const float* wsrc = (n0 < C) ? (W1 + (size_t)(k0 + kk) * C + (n0 + jb))
                                   : (W1 + (size_t)(C + k0 + kk) * C + (n0 - C + jb));
#pragma unroll
      for (int i = 0; i < 4; ++i)
        *(float4*)&wS[kk][jb + i * 4] = *(const float4*)(wsrc + i * 4);
    }
    __syncthreads();
#pragma unroll 8
    for (int k = 0; k < 64; ++k) {
      f32x4 a = *(const f32x4*)&xT[k][r0];
      f32x4 b = *(const f32x4*)&wS[k][c0];
#pragma unroll
      for (int i = 0; i < 4; ++i)
#pragma unroll
        for (int j = 0; j < 4; ++j) acc[i][j] = fmaf(a[i], b[j], acc[i][j]);
    }
    __syncthreads();
  }
  float* dst = (n0 < C) ? At : Bt;
  int ch0 = (n0 + c0) & (C - 1);
  float s1[4];
#pragma unroll
  for (int j = 0; j < 4; ++j) s1[j] = gamma1[ch0 + j] * rsqrtf(var1[ch0 + j] + EPS);
#pragma unroll
  for (int i = 0; i < 4; ++i) {
    float4 v = make_float4(acc[i][0] * s1[0], acc[i][1] * s1[1],
                           acc[i][2] * s1[2], acc[i][3] * s1[3]);
    *(float4*)&dst[(size_t)(m0 + r0 + i) * C + ch0] = v;
  }
}

// ---------------------------------------------------------------------------
// Kernel 5: per point h = relu(A~ + B~[idx] + beta_f) -> f16, y = h @ W2
// via mfma 16x16x32, BN2 affine, max over k -> out.
// ---------------------------------------------------------------------------
__global__ __launch_bounds__(256) void k_mlp(
    const float* __restrict__ At, const float* __restrict__ Bt,
    const int* __restrict__ knn, const float* __restrict__ W2,
    const float* __restrict__ b1, const float* __restrict__ mean1,
    const float* __restrict__ beta1, const float* __restrict__ gamma1,
    const float* __restrict__ var1, const float* __restrict__ b2,
    const float* __restrict__ mean2, const float* __restrict__ beta2,
    const float* __restrict__ gamma2, const float* __restrict__ var2,
    float* __restrict__ out) {
  __shared__ _Float16 hl[16][136];
  int t = threadIdx.x;
  int lane = t & 63;
  int wave = t >> 6;
  int hk = t >> 4;
  int hc = (t & 15) * 8;

  float beta_f[8];
#pragma unroll
  for (int e = 0; e < 8; ++e) {
    int c = hc + e;
    float s1 = gamma1[c] * rsqrtf(var1[c] + EPS);
    beta_f[e] = s1 * (b1[c] - mean1[c]) + beta1[c];
  }
  float s2r[4], t2r[4];
#pragma unroll
  for (int nt = 0; nt < 4; ++nt) {
    int ch = wave * 64 + nt * 16 + (lane & 15);
    float s2 = gamma2[ch] * rsqrtf(var2[ch] + EPS);
    s2r[nt] = s2;
    t2r[nt] = s2 * (b2[ch] - mean2[ch]) + beta2[ch];
  }
  half8 bf[4][4];
#pragma unroll
  for (int nt = 0; nt < 4; ++nt)
#pragma unroll
    for (int ks = 0; ks < 4; ++ks) {
      int colc = wave * 64 + nt * 16 + (lane & 15);
      int kb = ks * 32 + (lane >> 4) * 8;
      half8 hv;
#pragma unroll
      for (int i = 0; i < 8; ++i) hv[i] = (_Float16)W2[(size_t)(kb + i) * CO + colc];
      bf[nt][ks] = hv;
    }

  int p0 = blockIdx.x * 16;
  for (int p = 0; p < 16; ++p) {
    int pt = p0 + p;
    int m = knn[(size_t)pt * KNN + hk];
    int bb = pt >> 12;
    const float* arow = At + (size_t)pt * C + hc;
    const float* brow = Bt + ((size_t)(bb << 12) + m) * C + hc;
    float4 a0 = *(const float4*)(arow);
    float4 a1 = *(const float4*)(arow + 4);
    float4 g0 = *(const float4*)(brow);
    float4 g1 = *(const float4*)(brow + 4);
    float vv[8] = {a0.x + g0.x, a0.y + g0.y, a0.z + g0.z, a0.w + g0.w,
                   a1.x + g1.x, a1.y + g1.y, a1.z + g1.z, a1.w + g1.w};
    half8 hh;
#pragma unroll
    for (int e = 0; e < 8; ++e) hh[e] = (_Float16)fmaxf(vv[e] + beta_f[e], 0.f);
    *(half8*)&hl[hk][hc] = hh;
    __syncthreads();

    f32x4 acc[4] = {};
    half8 af[4];
#pragma unroll
    for (int ks = 0; ks < 4; ++ks)
      af[ks] = *(const half8*)&hl[lane & 15][ks * 32 + (lane >> 4) * 8];
#pragma unroll
    for (int nt = 0; nt < 4; ++nt)
#pragma unroll
      for (int ks = 0; ks < 4; ++ks)
        acc[nt] = __builtin_amdgcn_mfma_f32_16x16x32_f16(af[ks], bf[nt][ks],
                                                         acc[nt], 0, 0, 0);
#pragma unroll
    for (int nt = 0; nt < 4; ++nt) {
      float v = fmaxf(fmaxf(acc[nt][0], acc[nt][1]), fmaxf(acc[nt][2], acc[nt][3]));
      v = fmaxf(v, __shfl_xor(v, 16));
      v = fmaxf(v, __shfl_xor(v, 32));
      float o = fmaf(v, s2r[nt], t2r[nt]);
      if (lane < 16) out[(size_t)pt * CO + wave * 64 + nt * 16 + lane] = o;
    }
    __syncthreads();
  }
}

// ---------------------------------------------------------------------------
extern "C" void kernel_launch(void* const* d_in, const int* in_sizes, int n_in,
                              void* d_out, int out_size, void* d_ws, size_t ws_size,
                              hipStream_t stream) {
  const float* x = (const float*)d_in[0];
  const float* W1 = (const float*)d_in[1];
  const float* b1 = (const float*)d_in[2];
  const float* gamma1 = (const float*)d_in[3];
  const float* beta1 = (const float*)d_in[4];
  const float* mean1 = (const float*)d_in[5];
  const float* var1 = (const float*)d_in[6];
  const float* W2 = (const float*)d_in[7];
  const float* b2 = (const float*)d_in[8];
  const float* gamma2 = (const float*)d_in[9];
  const float* beta2 = (const float*)d_in[10];
  const float* mean2 = (const float*)d_in[11];
  const float* var2 = (const float*)d_in[12];
  float* out = (float*)d_out;

  char* base = (char*)d_ws;
  // region A (8 MB): pd+pi during topk, then At for the MLP
  float* At = (float*)base;                       // [M][128]
  float* pd = (float*)base;                       // [64][M] transposed
  int* pi = (int*)(base + (size_t)64 * M * 4);    // [64][M]
  // region B (8 MB): xh+xm during topk, then Bt
  float* Bt = (float*)(base + (size_t)M * C * 4);             // [M][128]
  _Float16* xh = (_Float16*)(base + (size_t)M * C * 4);       // [M][128] f16
  _Float16* xm = xh + (size_t)M * C;                          // [M][128] f16
  // tail
  float* sq = (float*)(base + (size_t)2 * M * C * 4);         // [M]
  int* knn = (int*)(sq + M);                                  // [M][16]

  k_cvt<<<dim3(M / 64), dim3(256), 0, stream>>>(x, xh, xm, sq);
  k_topk<<<dim3(B * 64 * NCHUNK), dim3(256), 0, stream>>>(xh, xm, sq, pd, pi);
  k_merge<<<dim3(M / 256), dim3(256), 0, stream>>>(pd, pi, knn);
  k_gemm1<<<dim3(M / 64, CO / 64), dim3(256), 0, stream>>>(x, W1, gamma1, var1, At, Bt);
  k_mlp<<<dim3(M / 16), dim3(256), 0, stream>>>(At, Bt, knn, W2, b1, mean1, beta1,
                                                gamma1, var1, b2, mean2, beta2,
                                                gamma2, var2, out);
}